// Round 4
// baseline (129.840 us; speedup 1.0000x reference)
//
#include <hip/hip_runtime.h>

#define B_ 8
#define H_ 512
#define W_ 1024
#define NPX (B_*H_*W_)

// ---------------- Stage 1 geometry ----------------
#define TILE 32
#define HD 4
#define RD 40
#define HB 7
#define RB 46
#define HP 8
#define RP 48

__device__ __forceinline__ int clampi(int v, int lo, int hi) {
    return v < lo ? lo : (v > hi ? hi : v);
}
__device__ __forceinline__ int imax(int a, int b) { return a > b ? a : b; }
__device__ __forceinline__ int imin(int a, int b) { return a < b ? a : b; }

// ---- K1: per-pixel boundary bitmap (ballot words, 1 bit/px) ----
__global__ __launch_bounds__(256)
void k_flags(const int* __restrict__ pred, unsigned long long* __restrict__ bmap)
{
    const int tid = threadIdx.x;
    const int idx = blockIdx.x * 256 + tid;          // block = 256 consecutive px in one row
    const int gx   = idx & (W_ - 1);
    const int grow = idx >> 10;                      // global row (images concatenated)
    const int yi   = grow & (H_ - 1);
    const int rup  = (yi == 0)      ? grow : grow - 1;
    const int rdn  = (yi == H_ - 1) ? grow : grow + 1;

    const int c = pred[(size_t)grow * W_ + gx];
    const int u = pred[(size_t)rup  * W_ + gx];
    const int d = pred[(size_t)rdn  * W_ + gx];
    const int vmax = imax(c, imax(u, d));
    int       vmin = imin(c, imin(u, d));

    const int lane = tid & 63;
    int cL = __shfl_up(c, 1);
    int vL = __shfl_up(vmin, 1);
    int cR = __shfl_down(c, 1);
    int vR = __shfl_down(vmin, 1);
    if (lane == 0) {
        if (gx > 0) {
            cL = pred[(size_t)grow * W_ + gx - 1];
            int u2 = pred[(size_t)rup * W_ + gx - 1];
            int d2 = pred[(size_t)rdn * W_ + gx - 1];
            vL = imin(cL, imin(u2, d2));
        } else { cL = c; vL = vmin; }
    }
    if (lane == 63) {
        if (gx < W_ - 1) {
            cR = pred[(size_t)grow * W_ + gx + 1];
            int u2 = pred[(size_t)rup * W_ + gx + 1];
            int d2 = pred[(size_t)rdn * W_ + gx + 1];
            vR = imin(cR, imin(u2, d2));
        } else { cR = c; vR = vmin; }
    }
    const int mx = imax(vmax, imax(cL, cR));      // max over cross (incl. center)
    const int mn = imin(vmin, imin(vL, vR));      // min over 3x3
    const bool boundary = (mx > c) || (mn < c);
    unsigned long long bal = __ballot(boundary);
    if (lane == 0) bmap[idx >> 6] = bal;
}

// ---- K2: per-tile identity check (b0==1 on tile+1 halo) -> copy, else general path ----
__global__ __launch_bounds__(256)
void k_stage1(const float* __restrict__ xg, const int* __restrict__ predg,
              const unsigned long long* __restrict__ bmap, int use_bmap,
              float* __restrict__ outg)
{
    __shared__ int sFlag;
    __shared__ int sScratch[3200];                 // union: sPred (9216B) / sHX+sHM (12800B)
    __shared__ unsigned long long sB[4][RB];
    __shared__ float sA[RD * RD];
    __shared__ float sC[RD * RD];

    int*   sPred = sScratch;
    float* sHX = (float*)sScratch;
    float* sHM = (float*)sScratch + RD * RD;

    const int tid = threadIdx.x;
    const int x0 = blockIdx.x * TILE;
    const int y0 = blockIdx.y * TILE;
    const size_t plane = (size_t)H_ * W_;
    const int*   pp = predg + blockIdx.z * plane;
    const float* xp = xg    + blockIdx.z * plane;
    float*       op = outg  + blockIdx.z * plane;

    // ---- identity check from bitmap ----
    if (tid < 64) {
        bool ok = (use_bmap != 0);
        if (ok) {
            const int rlo = (y0 > 0) ? y0 - 1 : 0;
            const int rhi = (y0 + TILE < H_) ? y0 + TILE : H_ - 1;
            const int row = rlo + tid;
            if (row <= rhi) {
                const int clo = (x0 > 0) ? x0 - 1 : 0;
                const int chi = (x0 + TILE < W_) ? x0 + TILE : W_ - 1;
                const unsigned long long* rb = bmap + ((size_t)blockIdx.z * H_ + row) * (W_ / 64);
                const int w0 = clo >> 6, w1 = chi >> 6;
                for (int w = w0; w <= w1; ++w) {
                    int lo = (clo > (w << 6)) ? (clo - (w << 6)) : 0;
                    int hi = (chi < ((w << 6) + 63)) ? (chi - (w << 6)) : 63;
                    unsigned long long m = (lo == 0 && hi == 63) ? ~0ULL
                                         : ((((1ULL << (hi - lo + 1)) - 1ULL) << lo));
                    if ((rb[w] & m) != m) ok = false;
                }
            }
        }
        unsigned long long all = __ballot(ok);
        if (tid == 0) sFlag = (all == ~0ULL) ? 1 : 0;
    }
    __syncthreads();

    if (sFlag) {  // identity: out = x on this tile
        int ty = tid >> 3, tx4 = (tid & 7) * 4;
        const float4 v = *(const float4*)(xp + (size_t)(y0 + ty) * W_ + (x0 + tx4));
        *(float4*)(op + (size_t)(y0 + ty) * W_ + (x0 + tx4)) = v;
        return;
    }

    // =================== general path (rare) ===================
    const bool leftB  = (x0 == 0), rightB = (x0 + TILE == W_);
    const bool topB   = (y0 == 0), botB   = (y0 + TILE == H_);
    const bool borderB = leftB || rightB || topB || botB;

    for (int i = tid; i < RP * RP; i += 256) {
        int ry = i / RP, rx = i - ry * RP;
        int gy = y0 - HP + ry, gx = x0 - HP + rx;
        sPred[i] = (gy >= 0 && gy < H_ && gx >= 0 && gx < W_) ? pp[(size_t)gy * W_ + gx] : -1;
    }
    for (int i = tid; i < RD * RD; i += 256) {
        int ry = i / RD, rx = i - ry * RD;
        int gy = clampi(y0 - HD + ry, 0, H_ - 1);
        int gx = clampi(x0 - HD + rx, 0, W_ - 1);
        sA[i] = xp[(size_t)gy * W_ + gx];
    }
    __syncthreads();

    {   // b0 via ballot
        const int lane = tid & 63, wv = tid >> 6;
        for (int row = wv; row < RB; row += 4) {
            bool bp = false;
            if (lane < RB) {
                const int py = row + 1, px = lane + 1;
                int c = sPred[py * RP + px];
                if (c >= 0) {
                    int up = sPred[(py - 1) * RP + px];
                    int dn = sPred[(py + 1) * RP + px];
                    int lf = sPred[py * RP + px - 1];
                    int rt = sPred[py * RP + px + 1];
                    int ul = sPred[(py - 1) * RP + px - 1];
                    int ur = sPred[(py - 1) * RP + px + 1];
                    int dl = sPred[(py + 1) * RP + px - 1];
                    int dr = sPred[(py + 1) * RP + px + 1];
                    int mx = imax(imax(up, dn), imax(lf, rt));
                    int Bv = 0x7fffffff;
                    int mn = imin(imin(imin(up < 0 ? Bv : up, dn < 0 ? Bv : dn),
                                       imin(lf < 0 ? Bv : lf, rt < 0 ? Bv : rt)),
                                  imin(imin(ul < 0 ? Bv : ul, ur < 0 ? Bv : ur),
                                       imin(dl < 0 ? Bv : dl, dr < 0 ? Bv : dr)));
                    bp = (mx > c) || (mn < c);
                }
            }
            unsigned long long bal = __ballot(bp);
            if (lane == 0) sB[0][row] = bal;
        }
    }

    #pragma unroll
    for (int lvl = 1; lvl < 4; ++lvl) {
        __syncthreads();
        if (tid < RB) {
            unsigned long long c = sB[lvl - 1][tid];
            unsigned long long u = (tid > 0)      ? sB[lvl - 1][tid - 1] : 0ULL;
            unsigned long long d = (tid < RB - 1) ? sB[lvl - 1][tid + 1] : 0ULL;
            sB[lvl][tid] = c | (c << 1) | (c >> 1) | u | d;
        }
    }
    __syncthreads();

    if (borderB) {
        const bool act = tid < 4 * RB;
        unsigned long long val = 0; int lvl = 0, row = 0;
        if (act) {
            lvl = tid / RB; row = tid - lvl * RB;
            int srcRow = clampi(row, topB ? HB : 0, botB ? (RB - 1 - HB) : RB - 1);
            val = sB[lvl][srcRow];
            if (leftB) {
                unsigned long long b = (val >> HB) & 1ULL;
                unsigned long long lo = (1ULL << HB) - 1;
                val = (val & ~lo) | (b ? lo : 0ULL);
            }
            if (rightB) {
                const int jb = RB - 1 - HB;
                unsigned long long b = (val >> jb) & 1ULL;
                unsigned long long keep = (1ULL << (jb + 1)) - 1;
                unsigned long long hi = (((1ULL << RB) - 1) & ~keep);
                val = (val & keep) | (b ? hi : 0ULL);
            }
        }
        __syncthreads();
        if (act) sB[lvl][row] = val;
    }
    __syncthreads();

    float* cur = sA;
    float* nxt = sC;
    #pragma unroll
    for (int it = 0; it < 4; ++it) {
        const int r = 3 - it;
        const unsigned long long* br = sB[r];

        for (int i = tid; i < RD * RD; i += 256) {
            int ry = i / RD, rx = i - ry * RD;
            unsigned long long row = br[ry + (HB - HD)];
            int rxm = rx > 0 ? rx - 1 : 0;
            int rxp = rx < RD - 1 ? rx + 1 : RD - 1;
            float m0 = ((row >> (rx + 2)) & 1ULL) ? 0.f : 1.f;
            float m1 = ((row >> (rx + 3)) & 1ULL) ? 0.f : 1.f;
            float m2 = ((row >> (rx + 4)) & 1ULL) ? 0.f : 1.f;
            float a0 = cur[ry * RD + rxm];
            float a1 = cur[ry * RD + rx];
            float a2 = cur[ry * RD + rxp];
            sHX[i] = m0 * a0 + m1 * a1 + m2 * a2;
            sHM[i] = m0 + m1 + m2;
        }
        __syncthreads();

        for (int i = tid; i < 38 * 38; i += 256) {
            int q = i / 38;
            int ry = 1 + q, rx = 1 + (i - q * 38);
            int idx = ry * RD + rx;
            float n = sHM[idx - RD] + sHM[idx] + sHM[idx + RD];
            float y = sHX[idx - RD] + sHX[idx] + sHX[idx + RD];
            float c = cur[idx];
            unsigned long long row = br[ry + (HB - HD)];
            bool masked = ((row >> (rx + 3)) & 1ULL) != 0ULL;
            float avg = y * __builtin_amdgcn_rcpf(n);
            nxt[idx] = (masked && n > 0.5f) ? avg : c;
        }
        __syncthreads();

        if (borderB) {
            for (int i = tid; i < RD * RD; i += 256) {
                int ry = i / RD, rx = i - ry * RD;
                int ryc = clampi(ry, topB ? HD : 0, botB ? (RD - 1 - HD) : RD - 1);
                int rxc = clampi(rx, leftB ? HD : 0, rightB ? (RD - 1 - HD) : RD - 1);
                if (ryc != ry || rxc != rx) nxt[i] = nxt[ryc * RD + rxc];
            }
        }
        __syncthreads();
        float* t = cur; cur = nxt; nxt = t;
    }

    for (int i = tid; i < TILE * TILE; i += 256) {
        int ty = i >> 5, tx = i & 31;
        op[(size_t)(y0 + ty) * W_ + (x0 + tx)] = cur[(ty + HD) * RD + (tx + HD)];
    }
}

// ---------------- Gaussian weights ----------------
#define GW0 0.39905027965f
#define GW1 0.24203622800f
#define GW2 0.05400558260f
#define GW3 0.00443304810f

// ---- H pass: block = one row (1024 px), thread = 4 px, 11 aligned float4 loads ----
__global__ __launch_bounds__(256)
void gaussH(const float* __restrict__ in, float* __restrict__ out)
{
    const int tid = threadIdx.x;
    const float* rp = in  + (size_t)blockIdx.x * W_;
    float*       wp = out + (size_t)blockIdx.x * W_;
    const int gx0 = tid * 4;

    float4 o;
    if (tid >= 5 && tid <= 250) {
        const float4* vp = (const float4*)(rp + gx0 - 20);
        float4 fm5 = vp[0], fm4 = vp[1], fm3 = vp[2], fm2 = vp[3], fm1 = vp[4];
        float4 f0 = vp[5], f1 = vp[6], f2 = vp[7], f3 = vp[8], f4 = vp[9], f5 = vp[10];
        o.x = GW0 * f0.x + GW1 * (fm2.z + f1.z) + GW2 * (fm3.x + f3.x) + GW3 * (fm5.z + f4.z);
        o.y = GW0 * f0.y + GW1 * (fm2.w + f1.w) + GW2 * (fm3.y + f3.y) + GW3 * (fm5.w + f4.w);
        o.z = GW0 * f0.z + GW1 * (fm1.x + f2.x) + GW2 * (fm3.z + f3.z) + GW3 * (fm4.x + f5.x);
        o.w = GW0 * f0.w + GW1 * (fm1.y + f2.y) + GW2 * (fm3.w + f3.w) + GW3 * (fm4.y + f5.y);
    } else {
        float r[4];
        #pragma unroll
        for (int j = 0; j < 4; ++j) {
            int gx = gx0 + j;
            r[j] = GW3 * (rp[clampi(gx - 18, 0, W_ - 1)] + rp[clampi(gx + 18, 0, W_ - 1)])
                 + GW2 * (rp[clampi(gx - 12, 0, W_ - 1)] + rp[clampi(gx + 12, 0, W_ - 1)])
                 + GW1 * (rp[clampi(gx - 6,  0, W_ - 1)] + rp[clampi(gx + 6,  0, W_ - 1)])
                 + GW0 *  rp[gx];
        }
        o.x = r[0]; o.y = r[1]; o.z = r[2]; o.w = r[3];
    }
    *(float4*)(wp + gx0) = o;
}

// ---- V pass: block = one output row, thread = 4 px, 7 aligned float4 loads ----
__global__ __launch_bounds__(256)
void gaussV(const float* __restrict__ in, float* __restrict__ out)
{
    const int tid = threadIdx.x;
    const int y   = blockIdx.x & (H_ - 1);
    const int img = blockIdx.x >> 9;
    const float* pl = in  + (size_t)img * H_ * W_;
    float*       wp = out + (size_t)blockIdx.x * W_;
    const int gx0 = tid * 4;

    const float* r0 = pl + (size_t)clampi(y - 18, 0, H_ - 1) * W_ + gx0;
    const float* r1 = pl + (size_t)clampi(y - 12, 0, H_ - 1) * W_ + gx0;
    const float* r2 = pl + (size_t)clampi(y - 6,  0, H_ - 1) * W_ + gx0;
    const float* r3 = pl + (size_t)y * W_ + gx0;
    const float* r4 = pl + (size_t)clampi(y + 6,  0, H_ - 1) * W_ + gx0;
    const float* r5 = pl + (size_t)clampi(y + 12, 0, H_ - 1) * W_ + gx0;
    const float* r6 = pl + (size_t)clampi(y + 18, 0, H_ - 1) * W_ + gx0;

    float4 a0 = *(const float4*)r0, a1 = *(const float4*)r1, a2 = *(const float4*)r2;
    float4 a3 = *(const float4*)r3, a4 = *(const float4*)r4, a5 = *(const float4*)r5;
    float4 a6 = *(const float4*)r6;

    float4 o;
    o.x = GW3 * (a0.x + a6.x) + GW2 * (a1.x + a5.x) + GW1 * (a2.x + a4.x) + GW0 * a3.x;
    o.y = GW3 * (a0.y + a6.y) + GW2 * (a1.y + a5.y) + GW1 * (a2.y + a4.y) + GW0 * a3.y;
    o.z = GW3 * (a0.z + a6.z) + GW2 * (a1.z + a5.z) + GW1 * (a2.z + a4.z) + GW0 * a3.z;
    o.w = GW3 * (a0.w + a6.w) + GW2 * (a1.w + a5.w) + GW1 * (a2.w + a4.w) + GW0 * a3.w;
    *(float4*)(wp + gx0) = o;
}

// fallback tiled stage2 (only if ws can't hold two planes)
#define GTW 64
#define GTH 64
#define GHALO 18
#define GRH (GTH + 2*GHALO)

__global__ __launch_bounds__(256)
void bsws_stage2_tiled(const float* __restrict__ ing, float* __restrict__ outg)
{
    __shared__ float sH[GRH][GTW];
    const int tid = threadIdx.x;
    const int x0 = blockIdx.x * GTW;
    const int y0 = blockIdx.y * GTH;
    const size_t plane = (size_t)H_ * W_;
    const float* ip = ing  + blockIdx.z * plane;
    float*       op = outg + blockIdx.z * plane;

    for (int i = tid; i < GRH * GTW; i += 256) {
        int row = i >> 6, col = i & 63;
        int gy = clampi(y0 - GHALO + row, 0, H_ - 1);
        const float* rowp = ip + (size_t)gy * W_;
        int gx = x0 + col;
        float acc = GW3 * (rowp[clampi(gx - 18, 0, W_ - 1)] + rowp[clampi(gx + 18, 0, W_ - 1)])
                  + GW2 * (rowp[clampi(gx - 12, 0, W_ - 1)] + rowp[clampi(gx + 12, 0, W_ - 1)])
                  + GW1 * (rowp[clampi(gx - 6,  0, W_ - 1)] + rowp[clampi(gx + 6,  0, W_ - 1)])
                  + GW0 *  rowp[gx];
        sH[row][col] = acc;
    }
    __syncthreads();
    for (int i = tid; i < GTH * GTW; i += 256) {
        int ty = i >> 6, tx = i & 63;
        float acc = GW3 * (sH[ty][tx]      + sH[ty + 36][tx])
                  + GW2 * (sH[ty + 6][tx]  + sH[ty + 30][tx])
                  + GW1 * (sH[ty + 12][tx] + sH[ty + 24][tx])
                  + GW0 *  sH[ty + 18][tx];
        op[(size_t)(y0 + ty) * W_ + (x0 + tx)] = acc;
    }
}

extern "C" void kernel_launch(void* const* d_in, const int* in_sizes, int n_in,
                              void* d_out, int out_size, void* d_ws, size_t ws_size,
                              hipStream_t stream) {
    const float* x    = (const float*)d_in[0];
    const int*   pred = (const int*)d_in[1];
    float*       out  = (float*)d_out;
    float*       mid  = (float*)d_ws;

    const size_t plane_bytes = (size_t)NPX * 4;
    const size_t bmap_bytes  = (size_t)NPX / 8;

    if (ws_size >= 2 * plane_bytes + bmap_bytes) {
        float* midH = mid + NPX;
        unsigned long long* bmap = (unsigned long long*)((char*)d_ws + 2 * plane_bytes);
        k_flags<<<NPX / 256, 256, 0, stream>>>(pred, bmap);
        k_stage1<<<dim3(W_ / TILE, H_ / TILE, B_), dim3(256), 0, stream>>>(x, pred, bmap, 1, mid);
        gaussH<<<B_ * H_, 256, 0, stream>>>(mid, midH);
        gaussV<<<B_ * H_, 256, 0, stream>>>(midH, out);
    } else if (ws_size >= 2 * plane_bytes) {
        float* midH = mid + NPX;
        k_stage1<<<dim3(W_ / TILE, H_ / TILE, B_), dim3(256), 0, stream>>>(x, pred, nullptr, 0, mid);
        gaussH<<<B_ * H_, 256, 0, stream>>>(mid, midH);
        gaussV<<<B_ * H_, 256, 0, stream>>>(midH, out);
    } else {
        k_stage1<<<dim3(W_ / TILE, H_ / TILE, B_), dim3(256), 0, stream>>>(x, pred, nullptr, 0, mid);
        bsws_stage2_tiled<<<dim3(W_ / GTW, H_ / GTH, B_), dim3(256), 0, stream>>>(mid, out);
    }
}

// Round 5
// 128.995 us; speedup vs baseline: 1.0066x; 1.0066x over previous
//
#include <hip/hip_runtime.h>

#define B_ 8
#define H_ 512
#define W_ 1024
#define NPX (B_*H_*W_)

// ---------------- Stage 1 geometry ----------------
#define TILE 32
#define HD 4
#define RD 40
#define HB 7
#define RB 46
#define HP 8
#define RP 48
#define TP 36                 // tile+2 pred region for the identity check

__device__ __forceinline__ int clampi(int v, int lo, int hi) {
    return v < lo ? lo : (v > hi ? hi : v);
}
__device__ __forceinline__ int imax(int a, int b) { return a > b ? a : b; }
__device__ __forceinline__ int imin(int a, int b) { return a < b ? a : b; }

// K1: per-tile identity check (b0==1 on tile+1 halo). Clean tiles: write flag=0 only
// (flags mode) or copy x->mid (copy mode, flags==nullptr). Dirty tiles: general path.
__global__ __launch_bounds__(256)
void k_stage1(const float* __restrict__ xg, const int* __restrict__ predg,
              float* __restrict__ midg, unsigned char* __restrict__ flags)
{
    __shared__ int sScratch[3200];              // union: pred36 / pred48 / sHX+sHM
    __shared__ unsigned long long sB[4][RB];
    __shared__ float sA[RD * RD];
    __shared__ float sC[RD * RD];
    __shared__ int sV[4];

    int*   sPred = sScratch;
    float* sHX = (float*)sScratch;
    float* sHM = (float*)sScratch + RD * RD;

    const int tid = threadIdx.x;
    const int x0 = blockIdx.x * TILE;
    const int y0 = blockIdx.y * TILE;
    const size_t plane = (size_t)H_ * W_;
    const int*   pp = predg + blockIdx.z * plane;
    const float* xp = xg    + blockIdx.z * plane;
    float*       op = midg  + blockIdx.z * plane;

    // ---- load pred tile+2 (sentinel -1 OOB) ----
    for (int i = tid; i < TP * TP; i += 256) {
        int ry = i / TP, rx = i - ry * TP;
        int gy = y0 - 2 + ry, gx = x0 - 2 + rx;
        sPred[i] = (gy >= 0 && gy < H_ && gx >= 0 && gx < W_) ? pp[(size_t)gy * W_ + gx] : -1;
    }
    __syncthreads();

    // ---- identity check: every in-image px of tile+1 halo must be boundary ----
    const int lane = tid & 63, wv = tid >> 6;
    unsigned long long acc = 0ULL;
    for (int r = wv; r < TILE + 2; r += 4) {
        bool viol = false;
        if (lane < TILE + 2) {
            int gy = y0 - 1 + r, gx = x0 - 1 + lane;
            if (gy >= 0 && gy < H_ && gx >= 0 && gx < W_) {
                const int py = r + 1, px = lane + 1;
                int c  = sPred[py * TP + px];
                int up = sPred[(py - 1) * TP + px];
                int dn = sPred[(py + 1) * TP + px];
                int lf = sPred[py * TP + px - 1];
                int rt = sPred[py * TP + px + 1];
                int ul = sPred[(py - 1) * TP + px - 1];
                int ur = sPred[(py - 1) * TP + px + 1];
                int dl = sPred[(py + 1) * TP + px - 1];
                int dr = sPred[(py + 1) * TP + px + 1];
                int mx = imax(imax(up, dn), imax(lf, rt));
                int Bv = 0x7fffffff;
                int mn = imin(imin(imin(up < 0 ? Bv : up, dn < 0 ? Bv : dn),
                                   imin(lf < 0 ? Bv : lf, rt < 0 ? Bv : rt)),
                              imin(imin(ul < 0 ? Bv : ul, ur < 0 ? Bv : ur),
                                   imin(dl < 0 ? Bv : dl, dr < 0 ? Bv : dr)));
                viol = !((mx > c) || (mn < c));
            }
        }
        acc |= __ballot(viol);
    }
    if (lane == 0) sV[wv] = (acc != 0ULL) ? 1 : 0;
    __syncthreads();
    const bool dirty = (sV[0] | sV[1] | sV[2] | sV[3]) != 0;

    const int tileId = (((blockIdx.z << 4) + blockIdx.y) << 5) + blockIdx.x;
    if (!dirty) {
        if (flags) {
            if (tid == 0) flags[tileId] = 0;
        } else {
            int ty = tid >> 3, tx4 = (tid & 7) * 4;
            const float4 v = *(const float4*)(xp + (size_t)(y0 + ty) * W_ + (x0 + tx4));
            *(float4*)(op + (size_t)(y0 + ty) * W_ + (x0 + tx4)) = v;
        }
        return;
    }

    // =================== general path (rare; validated r2-r4) ===================
    const bool leftB  = (x0 == 0), rightB = (x0 + TILE == W_);
    const bool topB   = (y0 == 0), botB   = (y0 + TILE == H_);
    const bool borderB = leftB || rightB || topB || botB;

    __syncthreads();
    for (int i = tid; i < RP * RP; i += 256) {
        int ry = i / RP, rx = i - ry * RP;
        int gy = y0 - HP + ry, gx = x0 - HP + rx;
        sPred[i] = (gy >= 0 && gy < H_ && gx >= 0 && gx < W_) ? pp[(size_t)gy * W_ + gx] : -1;
    }
    for (int i = tid; i < RD * RD; i += 256) {
        int ry = i / RD, rx = i - ry * RD;
        int gy = clampi(y0 - HD + ry, 0, H_ - 1);
        int gx = clampi(x0 - HD + rx, 0, W_ - 1);
        sA[i] = xp[(size_t)gy * W_ + gx];
    }
    __syncthreads();

    {   // b0 via ballot
        for (int row = wv; row < RB; row += 4) {
            bool bp = false;
            if (lane < RB) {
                const int py = row + 1, px = lane + 1;
                int c = sPred[py * RP + px];
                if (c >= 0) {
                    int up = sPred[(py - 1) * RP + px];
                    int dn = sPred[(py + 1) * RP + px];
                    int lf = sPred[py * RP + px - 1];
                    int rt = sPred[py * RP + px + 1];
                    int ul = sPred[(py - 1) * RP + px - 1];
                    int ur = sPred[(py - 1) * RP + px + 1];
                    int dl = sPred[(py + 1) * RP + px - 1];
                    int dr = sPred[(py + 1) * RP + px + 1];
                    int mx = imax(imax(up, dn), imax(lf, rt));
                    int Bv = 0x7fffffff;
                    int mn = imin(imin(imin(up < 0 ? Bv : up, dn < 0 ? Bv : dn),
                                       imin(lf < 0 ? Bv : lf, rt < 0 ? Bv : rt)),
                                  imin(imin(ul < 0 ? Bv : ul, ur < 0 ? Bv : ur),
                                       imin(dl < 0 ? Bv : dl, dr < 0 ? Bv : dr)));
                    bp = (mx > c) || (mn < c);
                }
            }
            unsigned long long bal = __ballot(bp);
            if (lane == 0) sB[0][row] = bal;
        }
    }

    #pragma unroll
    for (int lvl = 1; lvl < 4; ++lvl) {
        __syncthreads();
        if (tid < RB) {
            unsigned long long c = sB[lvl - 1][tid];
            unsigned long long u = (tid > 0)      ? sB[lvl - 1][tid - 1] : 0ULL;
            unsigned long long d = (tid < RB - 1) ? sB[lvl - 1][tid + 1] : 0ULL;
            sB[lvl][tid] = c | (c << 1) | (c >> 1) | u | d;
        }
    }
    __syncthreads();

    if (borderB) {
        const bool act = tid < 4 * RB;
        unsigned long long val = 0; int lvl = 0, row = 0;
        if (act) {
            lvl = tid / RB; row = tid - lvl * RB;
            int srcRow = clampi(row, topB ? HB : 0, botB ? (RB - 1 - HB) : RB - 1);
            val = sB[lvl][srcRow];
            if (leftB) {
                unsigned long long b = (val >> HB) & 1ULL;
                unsigned long long lo = (1ULL << HB) - 1;
                val = (val & ~lo) | (b ? lo : 0ULL);
            }
            if (rightB) {
                const int jb = RB - 1 - HB;
                unsigned long long b = (val >> jb) & 1ULL;
                unsigned long long keep = (1ULL << (jb + 1)) - 1;
                unsigned long long hi = (((1ULL << RB) - 1) & ~keep);
                val = (val & keep) | (b ? hi : 0ULL);
            }
        }
        __syncthreads();
        if (act) sB[lvl][row] = val;
    }
    __syncthreads();

    float* cur = sA;
    float* nxt = sC;
    #pragma unroll
    for (int it = 0; it < 4; ++it) {
        const int r = 3 - it;
        const unsigned long long* br = sB[r];

        for (int i = tid; i < RD * RD; i += 256) {
            int ry = i / RD, rx = i - ry * RD;
            unsigned long long row = br[ry + (HB - HD)];
            int rxm = rx > 0 ? rx - 1 : 0;
            int rxp = rx < RD - 1 ? rx + 1 : RD - 1;
            float m0 = ((row >> (rx + 2)) & 1ULL) ? 0.f : 1.f;
            float m1 = ((row >> (rx + 3)) & 1ULL) ? 0.f : 1.f;
            float m2 = ((row >> (rx + 4)) & 1ULL) ? 0.f : 1.f;
            float a0 = cur[ry * RD + rxm];
            float a1 = cur[ry * RD + rx];
            float a2 = cur[ry * RD + rxp];
            sHX[i] = m0 * a0 + m1 * a1 + m2 * a2;
            sHM[i] = m0 + m1 + m2;
        }
        __syncthreads();

        for (int i = tid; i < 38 * 38; i += 256) {
            int q = i / 38;
            int ry = 1 + q, rx = 1 + (i - q * 38);
            int idx = ry * RD + rx;
            float n = sHM[idx - RD] + sHM[idx] + sHM[idx + RD];
            float y = sHX[idx - RD] + sHX[idx] + sHX[idx + RD];
            float c = cur[idx];
            unsigned long long row = br[ry + (HB - HD)];
            bool masked = ((row >> (rx + 3)) & 1ULL) != 0ULL;
            float avg = y * __builtin_amdgcn_rcpf(n);
            nxt[idx] = (masked && n > 0.5f) ? avg : c;
        }
        __syncthreads();

        if (borderB) {
            for (int i = tid; i < RD * RD; i += 256) {
                int ry = i / RD, rx = i - ry * RD;
                int ryc = clampi(ry, topB ? HD : 0, botB ? (RD - 1 - HD) : RD - 1);
                int rxc = clampi(rx, leftB ? HD : 0, rightB ? (RD - 1 - HD) : RD - 1);
                if (ryc != ry || rxc != rx) nxt[i] = nxt[ryc * RD + rxc];
            }
        }
        __syncthreads();
        float* t = cur; cur = nxt; nxt = t;
    }

    for (int i = tid; i < TILE * TILE; i += 256) {
        int ty = i >> 5, tx = i & 31;
        op[(size_t)(y0 + ty) * W_ + (x0 + tx)] = cur[(ty + HD) * RD + (tx + HD)];
    }
    if (flags && tid == 0) flags[tileId] = 1;
}

// ---------------- Gaussian weights ----------------
#define GW0 0.39905027965f
#define GW1 0.24203622800f
#define GW2 0.05400558260f
#define GW3 0.00443304810f

// H pass reads x directly (stage1 output == x except on dirty tiles).
__global__ __launch_bounds__(256)
void gaussH(const float* __restrict__ x, const float* __restrict__ mid,
            const unsigned char* __restrict__ flags, float* __restrict__ out)
{
    __shared__ int sDirty;
    const int tid = threadIdx.x;
    const int grow = blockIdx.x;                     // img*512 + y
    const int img = grow >> 9, y = grow & (H_ - 1);
    const int fbase = (((img << 4) + (y >> 5)) << 5);

    if (tid == 0) sDirty = 0;
    __syncthreads();
    if (tid < 64) {
        int f = (tid < 32) ? (int)flags[fbase + tid] : 0;
        bool any = __any(f != 0);
        if (tid == 0 && any) sDirty = 1;
    }
    __syncthreads();

    const float* rp = x   + (size_t)grow * W_;
    float*       wp = out + (size_t)grow * W_;
    const int gx0 = tid * 4;
    float4 o;

    if (!sDirty) {
        if (tid >= 5 && tid <= 250) {
            const float4* vp = (const float4*)(rp + gx0 - 20);
            float4 fm5 = vp[0], fm4 = vp[1], fm3 = vp[2], fm2 = vp[3], fm1 = vp[4];
            float4 f0 = vp[5], f1 = vp[6], f2 = vp[7], f3 = vp[8], f4 = vp[9], f5 = vp[10];
            o.x = GW0 * f0.x + GW1 * (fm2.z + f1.z) + GW2 * (fm3.x + f3.x) + GW3 * (fm5.z + f4.z);
            o.y = GW0 * f0.y + GW1 * (fm2.w + f1.w) + GW2 * (fm3.y + f3.y) + GW3 * (fm5.w + f4.w);
            o.z = GW0 * f0.z + GW1 * (fm1.x + f2.x) + GW2 * (fm3.z + f3.z) + GW3 * (fm4.x + f5.x);
            o.w = GW0 * f0.w + GW1 * (fm1.y + f2.y) + GW2 * (fm3.w + f3.w) + GW3 * (fm4.y + f5.y);
        } else {
            float r[4];
            #pragma unroll
            for (int j = 0; j < 4; ++j) {
                int gx = gx0 + j;
                r[j] = GW3 * (rp[clampi(gx - 18, 0, W_ - 1)] + rp[clampi(gx + 18, 0, W_ - 1)])
                     + GW2 * (rp[clampi(gx - 12, 0, W_ - 1)] + rp[clampi(gx + 12, 0, W_ - 1)])
                     + GW1 * (rp[clampi(gx - 6,  0, W_ - 1)] + rp[clampi(gx + 6,  0, W_ - 1)])
                     + GW0 *  rp[gx];
            }
            o.x = r[0]; o.y = r[1]; o.z = r[2]; o.w = r[3];
        }
    } else {
        const float* rm = mid + (size_t)grow * W_;
        float r[4];
        #pragma unroll
        for (int j = 0; j < 4; ++j) {
            int gx = gx0 + j;
            float t[7];
            #pragma unroll
            for (int k = 0; k < 7; ++k) {
                int q = clampi(gx + (k - 3) * 6, 0, W_ - 1);
                t[k] = flags[fbase + (q >> 5)] ? rm[q] : rp[q];
            }
            r[j] = GW3 * (t[0] + t[6]) + GW2 * (t[1] + t[5]) + GW1 * (t[2] + t[4]) + GW0 * t[3];
        }
        o.x = r[0]; o.y = r[1]; o.z = r[2]; o.w = r[3];
    }
    *(float4*)(wp + gx0) = o;
}

__global__ __launch_bounds__(256)
void gaussV(const float* __restrict__ in, float* __restrict__ out)
{
    const int tid = threadIdx.x;
    const int y   = blockIdx.x & (H_ - 1);
    const int img = blockIdx.x >> 9;
    const float* pl = in  + (size_t)img * H_ * W_;
    float*       wp = out + (size_t)blockIdx.x * W_;
    const int gx0 = tid * 4;

    const float* r0 = pl + (size_t)clampi(y - 18, 0, H_ - 1) * W_ + gx0;
    const float* r1 = pl + (size_t)clampi(y - 12, 0, H_ - 1) * W_ + gx0;
    const float* r2 = pl + (size_t)clampi(y - 6,  0, H_ - 1) * W_ + gx0;
    const float* r3 = pl + (size_t)y * W_ + gx0;
    const float* r4 = pl + (size_t)clampi(y + 6,  0, H_ - 1) * W_ + gx0;
    const float* r5 = pl + (size_t)clampi(y + 12, 0, H_ - 1) * W_ + gx0;
    const float* r6 = pl + (size_t)clampi(y + 18, 0, H_ - 1) * W_ + gx0;

    float4 a0 = *(const float4*)r0, a1 = *(const float4*)r1, a2 = *(const float4*)r2;
    float4 a3 = *(const float4*)r3, a4 = *(const float4*)r4, a5 = *(const float4*)r5;
    float4 a6 = *(const float4*)r6;

    float4 o;
    o.x = GW3 * (a0.x + a6.x) + GW2 * (a1.x + a5.x) + GW1 * (a2.x + a4.x) + GW0 * a3.x;
    o.y = GW3 * (a0.y + a6.y) + GW2 * (a1.y + a5.y) + GW1 * (a2.y + a4.y) + GW0 * a3.y;
    o.z = GW3 * (a0.z + a6.z) + GW2 * (a1.z + a5.z) + GW1 * (a2.z + a4.z) + GW0 * a3.z;
    o.w = GW3 * (a0.w + a6.w) + GW2 * (a1.w + a5.w) + GW1 * (a2.w + a4.w) + GW0 * a3.w;
    *(float4*)(wp + gx0) = o;
}

// fallback tiled stage2 (only if ws can't hold two planes + flags)
#define GTW 64
#define GTH 64
#define GHALO 18
#define GRH (GTH + 2*GHALO)

__global__ __launch_bounds__(256)
void bsws_stage2_tiled(const float* __restrict__ ing, float* __restrict__ outg)
{
    __shared__ float sH[GRH][GTW];
    const int tid = threadIdx.x;
    const int x0 = blockIdx.x * GTW;
    const int y0 = blockIdx.y * GTH;
    const size_t plane = (size_t)H_ * W_;
    const float* ip = ing  + blockIdx.z * plane;
    float*       op = outg + blockIdx.z * plane;

    for (int i = tid; i < GRH * GTW; i += 256) {
        int row = i >> 6, col = i & 63;
        int gy = clampi(y0 - GHALO + row, 0, H_ - 1);
        const float* rowp = ip + (size_t)gy * W_;
        int gx = x0 + col;
        float acc = GW3 * (rowp[clampi(gx - 18, 0, W_ - 1)] + rowp[clampi(gx + 18, 0, W_ - 1)])
                  + GW2 * (rowp[clampi(gx - 12, 0, W_ - 1)] + rowp[clampi(gx + 12, 0, W_ - 1)])
                  + GW1 * (rowp[clampi(gx - 6,  0, W_ - 1)] + rowp[clampi(gx + 6,  0, W_ - 1)])
                  + GW0 *  rowp[gx];
        sH[row][col] = acc;
    }
    __syncthreads();
    for (int i = tid; i < GTH * GTW; i += 256) {
        int ty = i >> 6, tx = i & 63;
        float acc = GW3 * (sH[ty][tx]      + sH[ty + 36][tx])
                  + GW2 * (sH[ty + 6][tx]  + sH[ty + 30][tx])
                  + GW1 * (sH[ty + 12][tx] + sH[ty + 24][tx])
                  + GW0 *  sH[ty + 18][tx];
        op[(size_t)(y0 + ty) * W_ + (x0 + tx)] = acc;
    }
}

extern "C" void kernel_launch(void* const* d_in, const int* in_sizes, int n_in,
                              void* d_out, int out_size, void* d_ws, size_t ws_size,
                              hipStream_t stream) {
    const float* x    = (const float*)d_in[0];
    const int*   pred = (const int*)d_in[1];
    float*       out  = (float*)d_out;
    float*       mid  = (float*)d_ws;

    const size_t plane_bytes = (size_t)NPX * 4;
    const dim3 g1(W_ / TILE, H_ / TILE, B_);

    if (ws_size >= 2 * plane_bytes + 4096) {
        float* midH = mid + NPX;
        unsigned char* flags = (unsigned char*)d_ws + 2 * plane_bytes;
        k_stage1<<<g1, 256, 0, stream>>>(x, pred, mid, flags);
        gaussH<<<B_ * H_, 256, 0, stream>>>(x, mid, flags, midH);
        gaussV<<<B_ * H_, 256, 0, stream>>>(midH, out);
    } else {
        // copy mode + tiled gauss (needs 1 plane)
        k_stage1<<<g1, 256, 0, stream>>>(x, pred, mid, nullptr);
        bsws_stage2_tiled<<<dim3(W_ / GTW, H_ / GTH, B_), dim3(256), 0, stream>>>(mid, out);
    }
}